// Round 10
// baseline (249.293 us; speedup 1.0000x reference)
//
#include <hip/hip_runtime.h>
#include <hip/hip_bf16.h>

// ---- problem constants ----
#define N_GAUSS 4096
#define N_PTS   32768
#define GSTRIDE 28                  // floats per packed gaussian (7 x float4)
#define NCELL   4096                // 16^3 morton cells
#define NSLICE  512                 // gauss blocks: 512 x 64 sorted points

#define SH_C0  0.28209479177387814f
#define SH_C1  0.4886025119029199f

// Workspace layout (float index):
#define WS_GP     0                          // 4096*28 = 114688 floats
#define WS_GCUR   114688                     // int[4096] global scatter cursors
#define WS_CELLID 118784                     // int[32768]
#define WS_SPTS   151552                     // float4[32768] (16B aligned)
// total 282,624 floats = 1.13 MB

__device__ __forceinline__ int expand4(int b) {
    return (b & 1) | ((b & 2) << 2) | ((b & 4) << 4) | ((b & 8) << 6);
}

// ---------------------------------------------------------------------------
// N1: blocks 0..15: gaussian prep + zero gcursor | blocks 16..143: cell ids.
// Gaussian record (28 floats):
//   [0..2] center [3] Tg (skip iff dist^2 > Tg => w < e^-16*op)
//   [4..9] 0.5*precision [10] ln(op) [11] pad [12..27] SH pre-multiplied
// ---------------------------------------------------------------------------
__global__ __launch_bounds__(256) void prep_bin_kernel(
    const float* __restrict__ pts, const float* __restrict__ xyz,
    const float* __restrict__ sh_dc, const float* __restrict__ sh_rest,
    const float* __restrict__ scaling, const float* __restrict__ rotation,
    const float* __restrict__ opl, float* __restrict__ gp,
    int* __restrict__ cellid, int* __restrict__ gcursor)
{
    const int tid = threadIdx.x, bx = blockIdx.x;
    if (bx < 16) {
        gcursor[bx * 256 + tid] = 0;           // 16*256 = 4096 cursors zeroed

        int g = bx * 256 + tid;
        float s0 = scaling[3*g+0], s1 = scaling[3*g+1], s2 = scaling[3*g+2];
        float i0 = __expf(-2.0f * s0);
        float i1 = __expf(-2.0f * s1);
        float i2 = __expf(-2.0f * s2);
        float maxs2 = __expf(2.0f * fmaxf(s0, fmaxf(s1, s2)));

        float r = rotation[4*g+0], x = rotation[4*g+1];
        float y = rotation[4*g+2], z = rotation[4*g+3];
        float n = rsqrtf(r*r + x*x + y*y + z*z);
        r *= n; x *= n; y *= n; z *= n;
        float R00 = 1.f - 2.f*(y*y + z*z), R01 = 2.f*(x*y - r*z), R02 = 2.f*(x*z + r*y);
        float R10 = 2.f*(x*y + r*z), R11 = 1.f - 2.f*(x*x + z*z), R12 = 2.f*(y*z - r*x);
        float R20 = 2.f*(x*z - r*y), R21 = 2.f*(y*z + r*x), R22 = 1.f - 2.f*(x*x + y*y);

        float pxx = 0.5f*(R00*R00*i0 + R01*R01*i1 + R02*R02*i2);
        float pxy = 0.5f*(R00*R10*i0 + R01*R11*i1 + R02*R12*i2);
        float pxz = 0.5f*(R00*R20*i0 + R01*R21*i1 + R02*R22*i2);
        float pyy = 0.5f*(R10*R10*i0 + R11*R11*i1 + R12*R12*i2);
        float pyz = 0.5f*(R10*R20*i0 + R11*R21*i1 + R12*R22*i2);
        float pzz = 0.5f*(R20*R20*i0 + R21*R21*i1 + R22*R22*i2);

        float op   = 1.f / (1.f + __expf(-opl[g]));
        float lnop = __logf(op);
        // d2 > Tg => w < e^-16 ~ 1.1e-7; dropped total ~2e-3 << 4.1e-2 threshold
        float Tg   = 2.0f * maxs2 * (lnop + 16.0f);

        float* G = gp + (size_t)g * GSTRIDE;
        G[0] = xyz[3*g+0]; G[1] = xyz[3*g+1]; G[2] = xyz[3*g+2]; G[3] = Tg;
        G[4] = pxx; G[5] = pxy; G[6] = pxz; G[7] = pyy; G[8] = pyz; G[9] = pzz;
        G[10] = lnop; G[11] = 0.f;

        const float* sr = sh_rest + (size_t)g * 15;
        G[12] =  SH_C0 * sh_dc[g];
        G[13] = -SH_C1 * sr[0];
        G[14] =  SH_C1 * sr[1];
        G[15] = -SH_C1 * sr[2];
        G[16] =  1.0925484305920792f  * sr[3];
        G[17] = -1.0925484305920792f  * sr[4];
        G[18] =  0.31539156525252005f * sr[5];
        G[19] = -1.0925484305920792f  * sr[6];
        G[20] =  0.5462742152960396f  * sr[7];
        G[21] = -0.5900435899266435f  * sr[8];
        G[22] =  2.890611442640554f   * sr[9];
        G[23] = -0.4570457994644658f  * sr[10];
        G[24] =  0.3731763325901154f  * sr[11];
        G[25] = -0.4570457994644658f  * sr[12];
        G[26] =  1.445305721320277f   * sr[13];
        G[27] = -0.5900435899266435f  * sr[14];
    } else {
        int p = (bx - 16) * 256 + tid;
        float x = pts[3*p+0], y = pts[3*p+1], z = pts[3*p+2];
        int cx = min(15, max(0, (int)((x + 3.2f) * 2.5f)));
        int cy = min(15, max(0, (int)((y + 3.2f) * 2.5f)));
        int cz = min(15, max(0, (int)((z + 3.2f) * 2.5f)));
        cellid[p] = expand4(cx) | (expand4(cy) << 1) | (expand4(cz) << 2);
    }
}

// ---------------------------------------------------------------------------
// N2: 128 blocks; each block REDUNDANTLY builds the full histogram+exclusive
// scan from cellid (identical in every block), then scatters its own 256
// points using global per-cell cursors for unique positions.
// ---------------------------------------------------------------------------
__global__ __launch_bounds__(256) void scanscatter_kernel(
    const float* __restrict__ pts, const int* __restrict__ cellid,
    int* __restrict__ gcursor, float4* __restrict__ spts)
{
    __shared__ int s_start[NCELL];     // counts -> exclusive starts
    __shared__ int s_red[256];
    const int tid = threadIdx.x, bx = blockIdx.x;

    #pragma unroll
    for (int i = 0; i < 16; ++i) s_start[tid + i * 256] = 0;
    __syncthreads();
    #pragma unroll 4
    for (int i = 0; i < 128; ++i)
        atomicAdd(&s_start[cellid[i * 256 + tid]], 1);
    __syncthreads();

    // exclusive scan over 4096: 16 cells/thread local + block scan of totals
    int base = tid * 16;
    int c[16]; int tot = 0;
    #pragma unroll
    for (int i = 0; i < 16; ++i) { c[i] = s_start[base + i]; tot += c[i]; }
    s_red[tid] = tot;
    __syncthreads();
    for (int off = 1; off < 256; off <<= 1) {
        int v = (tid >= off) ? s_red[tid - off] : 0;
        __syncthreads();
        s_red[tid] += v;
        __syncthreads();
    }
    int run = s_red[tid] - tot;        // exclusive base for this thread's range
    #pragma unroll
    for (int i = 0; i < 16; ++i) { int cc = c[i]; s_start[base + i] = run; run += cc; }
    __syncthreads();

    // scatter own 256 points
    int p = bx * 256 + tid;
    float x = pts[3*p+0], y = pts[3*p+1], z = pts[3*p+2];
    int cell = cellid[p];
    int pos  = s_start[cell] + atomicAdd(&gcursor[cell], 1);
    spts[pos] = make_float4(x, y, z, __int_as_float(p));
}

// ---------------------------------------------------------------------------
// Eval body for one surviving record (R9-proven).
// ---------------------------------------------------------------------------
__device__ __forceinline__ void eval_one(
    const float* __restrict__ G, float dx, float dy, float dz, float d2,
    float& opac, float& sig)
{
    float vx = G[4]*dx + G[5]*dy + G[6]*dz;
    float vy = G[5]*dx + G[7]*dy + G[8]*dz;
    float vz = G[6]*dx + G[8]*dy + G[9]*dz;
    float maha = dx*vx + dy*vy + dz*vz;      // includes the 0.5
    float w = __expf(G[10] - maha);          // op * exp(-0.5*maha)
    opac += w;

    if (__any(w > 1e-9f)) {
        float rinv = rsqrtf(d2);
        float x = -dx * rinv, y = -dy * rinv, z = -dz * rinv;
        float xx = x*x, yy = y*y, zz = z*z;
        float xy = x*y, yz = y*z, xz = x*z;

        float res = G[12];
        res += y * G[13];
        res += z * G[14];
        res += x * G[15];
        res += xy * G[16];
        res += yz * G[17];
        res += (3.f*zz - 1.f) * G[18];
        res += xz * G[19];
        float xxmyy = xx - yy;
        res += xxmyy * G[20];
        res += y * (3.f*xx - yy) * G[21];
        res += (xy * z) * G[22];
        float f5z1 = 5.f*zz - 1.f;
        res += y * f5z1 * G[23];
        res += z * (5.f*zz - 3.f) * G[24];
        res += x * f5z1 * G[25];
        res += z * xxmyy * G[26];
        res += x * (xxmyy - 3.f*zz) * G[27];

        sig += w * fmaxf(res, 0.f);
    }
}

// ---------------------------------------------------------------------------
// N3: 512 blocks x 256 threads. Block = 64 sorted points x ALL 4096 gaussians.
// All 4 waves hold the same 64 points (lane = point); wave-private AABB via
// shfl; one shared cull list; wave w evals j = w (mod 4) with 2-way pipeline;
// LDS partial sum; wave 0 writes out[orig] directly. No split, no reduce node.
// ---------------------------------------------------------------------------
__global__ __launch_bounds__(256, 4) void gauss_kernel(
    const float4* __restrict__ spts, const float* __restrict__ gp,
    float* __restrict__ out)
{
    __shared__ int s_nact;
    __shared__ int s_act[N_GAUSS];            // 16 KB worst case
    __shared__ float s_part[4][64][2];

    const int tid  = threadIdx.x;
    const int lane = tid & 63;
    const int wv   = tid >> 6;
    const int bx   = blockIdx.x;

    float4 P = spts[bx * 64 + lane];
    const float px = P.x, py = P.y, pz = P.z;
    const int orig = __float_as_int(P.w);

    // wave-private AABB over the 64 points (identical in all 4 waves)
    float mnx = px, mxx = px, mny = py, mxy = py, mnz = pz, mxz = pz;
    #pragma unroll
    for (int off = 32; off >= 1; off >>= 1) {
        mnx = fminf(mnx, __shfl_xor(mnx, off));
        mxx = fmaxf(mxx, __shfl_xor(mxx, off));
        mny = fminf(mny, __shfl_xor(mny, off));
        mxy = fmaxf(mxy, __shfl_xor(mxy, off));
        mnz = fminf(mnz, __shfl_xor(mnz, off));
        mxz = fmaxf(mxz, __shfl_xor(mxz, off));
    }

    if (tid == 0) s_nact = 0;
    __syncthreads();

    // cull all 4096 gaussians: 16 per thread, coalesced q0 loads
    #pragma unroll 4
    for (int i = 0; i < 16; ++i) {
        const int g = i * 256 + tid;
        const float4 c = *(const float4*)(gp + (size_t)g * GSTRIDE);
        float ddx = fmaxf(0.f, fmaxf(mnx - c.x, c.x - mxx));
        float ddy = fmaxf(0.f, fmaxf(mny - c.y, c.y - mxy));
        float ddz = fmaxf(0.f, fmaxf(mnz - c.z, c.z - mxz));
        float dd2 = ddx*ddx + ddy*ddy + ddz*ddz;
        if (dd2 <= c.w) {
            int slot = atomicAdd(&s_nact, 1);
            s_act[slot] = g;
        }
    }
    __syncthreads();
    const int nact = s_nact;

    // wave wv handles list entries j ≡ wv (mod 4), 2-way pipelined
    float opac = 0.f, sig = 0.f;
    for (int j = wv; j < nact; j += 8) {
        const bool has1 = (j + 4 < nact);
        const int g0 = __builtin_amdgcn_readfirstlane(s_act[j]);
        const int g1 = __builtin_amdgcn_readfirstlane(s_act[has1 ? j + 4 : j]);
        const float* __restrict__ A = gp + (size_t)g0 * GSTRIDE;
        const float* __restrict__ B = gp + (size_t)g1 * GSTRIDE;

        float a0 = A[0], a1 = A[1], a2 = A[2], aT = A[3];
        float b0 = B[0], b1 = B[1], b2 = B[2], bT = B[3];
        float adx = px - a0, ady = py - a1, adz = pz - a2;
        float bdx = px - b0, bdy = py - b1, bdz = pz - b2;
        float ad2 = adx*adx + ady*ady + adz*adz;
        float bd2 = bdx*bdx + bdy*bdy + bdz*bdz;

        if (!__all(ad2 > aT)) eval_one(A, adx, ady, adz, ad2, opac, sig);
        if (has1 && !__all(bd2 > bT)) eval_one(B, bdx, bdy, bdz, bd2, opac, sig);
    }

    s_part[wv][lane][0] = opac;
    s_part[wv][lane][1] = sig;
    __syncthreads();

    if (tid < 64) {
        float o  = s_part[0][tid][0] + s_part[1][tid][0]
                 + s_part[2][tid][0] + s_part[3][tid][0];
        float sg = s_part[0][tid][1] + s_part[1][tid][1]
                 + s_part[2][tid][1] + s_part[3][tid][1];
        out[orig] = o;
        out[N_PTS + orig] = sg;
    }
}

extern "C" void kernel_launch(void* const* d_in, const int* in_sizes, int n_in,
                              void* d_out, int out_size, void* d_ws, size_t ws_size,
                              hipStream_t stream) {
    const float* pts      = (const float*)d_in[0];
    const float* xyz      = (const float*)d_in[3];
    const float* sh_dc    = (const float*)d_in[4];
    const float* sh_rest  = (const float*)d_in[5];
    const float* scaling  = (const float*)d_in[6];
    const float* rotation = (const float*)d_in[7];
    const float* opl      = (const float*)d_in[8];

    float*  out     = (float*)d_out;
    float*  wsf     = (float*)d_ws;
    float*  gp      = wsf + WS_GP;
    int*    gcursor = (int*)(wsf + WS_GCUR);
    int*    cellid  = (int*)(wsf + WS_CELLID);
    float4* spts    = (float4*)(wsf + WS_SPTS);

    prep_bin_kernel<<<dim3(144), dim3(256), 0, stream>>>(
        pts, xyz, sh_dc, sh_rest, scaling, rotation, opl, gp, cellid, gcursor);
    scanscatter_kernel<<<dim3(128), dim3(256), 0, stream>>>(
        pts, cellid, gcursor, spts);
    gauss_kernel<<<dim3(NSLICE), dim3(256), 0, stream>>>(spts, gp, out);
}

// Round 11
// 157.690 us; speedup vs baseline: 1.5809x; 1.5809x over previous
//
#include <hip/hip_runtime.h>
#include <hip/hip_bf16.h>

// ---- problem constants ----
#define N_GAUSS 4096
#define N_PTS   32768
#define BLOCK   256
#define NSPLIT  32                  // 128-gaussian segments; grid 128 x 32
#define SEGSZ   (N_GAUSS / NSPLIT)  // 128
#define NBLK_PT 128                 // 128 x 256 = 32768 points
#define GSTRIDE 28                  // floats per packed gaussian
#define NCELL   4096                // 16^3 morton cells

#define SH_C0  0.28209479177387814f
#define SH_C1  0.4886025119029199f

// Workspace layout (float index):
#define WS_GP   0                            // 4096*28 = 114688 floats
#define WS_SPTS 114688                       // float4[32768] = 131072 floats
#define WS_PART 245760                       // float2[4096*256] = 2097152 floats
// total 2,342,912 floats = 9.37 MB (R9 used 9.52 MB — known OK)

__device__ __forceinline__ int cell_of(float x, float y, float z) {
    int cx = min(15, max(0, (int)((x + 3.2f) * 2.5f)));
    int cy = min(15, max(0, (int)((y + 3.2f) * 2.5f)));
    int cz = min(15, max(0, (int)((z + 3.2f) * 2.5f)));
    // morton interleave
    int ex = (cx & 1) | ((cx & 2) << 2) | ((cx & 4) << 4) | ((cx & 8) << 6);
    int ey = (cy & 1) | ((cy & 2) << 2) | ((cy & 4) << 4) | ((cy & 8) << 6);
    int ez = (cz & 1) | ((cz & 2) << 2) | ((cz & 4) << 4) | ((cz & 8) << 6);
    return ex | (ey << 1) | (ez << 2);
}

// ---------------------------------------------------------------------------
// N1 (144 blocks x 256):
//  blocks 0..127  : deterministic sort-scatter. Each block redundantly bins
//                   ALL 32768 points (LDS hist) + counts points before its own
//                   chunk per cell; identical exclusive scan in every block;
//                   pos = start[cell] + pre[cell] + in-chunk-rank. Stable,
//                   cursor-free, no inter-block communication.
//  blocks 128..143: gaussian prep -> gp.
// Gaussian record (28 floats): [0..2] center [3] Tg cull threshold
//   [4..9] 0.5*precision [10] ln(op) [11] pad [12..27] SH pre-multiplied
// ---------------------------------------------------------------------------
__global__ __launch_bounds__(256) void setup_kernel(
    const float* __restrict__ pts, const float* __restrict__ xyz,
    const float* __restrict__ sh_dc, const float* __restrict__ sh_rest,
    const float* __restrict__ scaling, const float* __restrict__ rotation,
    const float* __restrict__ opl, float* __restrict__ gp,
    float4* __restrict__ spts)
{
    const int tid = threadIdx.x, bx = blockIdx.x;

    if (bx >= NBLK_PT) {
        // ---- gaussian prep ----
        int g = (bx - NBLK_PT) * 256 + tid;
        float s0 = scaling[3*g+0], s1 = scaling[3*g+1], s2 = scaling[3*g+2];
        float i0 = __expf(-2.0f * s0);
        float i1 = __expf(-2.0f * s1);
        float i2 = __expf(-2.0f * s2);
        float maxs2 = __expf(2.0f * fmaxf(s0, fmaxf(s1, s2)));

        float r = rotation[4*g+0], x = rotation[4*g+1];
        float y = rotation[4*g+2], z = rotation[4*g+3];
        float n = rsqrtf(r*r + x*x + y*y + z*z);
        r *= n; x *= n; y *= n; z *= n;
        float R00 = 1.f - 2.f*(y*y + z*z), R01 = 2.f*(x*y - r*z), R02 = 2.f*(x*z + r*y);
        float R10 = 2.f*(x*y + r*z), R11 = 1.f - 2.f*(x*x + z*z), R12 = 2.f*(y*z - r*x);
        float R20 = 2.f*(x*z - r*y), R21 = 2.f*(y*z + r*x), R22 = 1.f - 2.f*(x*x + y*y);

        float pxx = 0.5f*(R00*R00*i0 + R01*R01*i1 + R02*R02*i2);
        float pxy = 0.5f*(R00*R10*i0 + R01*R11*i1 + R02*R12*i2);
        float pxz = 0.5f*(R00*R20*i0 + R01*R21*i1 + R02*R22*i2);
        float pyy = 0.5f*(R10*R10*i0 + R11*R11*i1 + R12*R12*i2);
        float pyz = 0.5f*(R10*R20*i0 + R11*R21*i1 + R12*R22*i2);
        float pzz = 0.5f*(R20*R20*i0 + R21*R21*i1 + R22*R22*i2);

        float op   = 1.f / (1.f + __expf(-opl[g]));
        float lnop = __logf(op);
        // d2 > Tg => w < e^-16 ~ 1.1e-7; dropped total ~2e-3 << 4.1e-2 threshold
        float Tg   = 2.0f * maxs2 * (lnop + 16.0f);

        float* G = gp + (size_t)g * GSTRIDE;
        G[0] = xyz[3*g+0]; G[1] = xyz[3*g+1]; G[2] = xyz[3*g+2]; G[3] = Tg;
        G[4] = pxx; G[5] = pxy; G[6] = pxz; G[7] = pyy; G[8] = pyz; G[9] = pzz;
        G[10] = lnop; G[11] = 0.f;

        const float* sr = sh_rest + (size_t)g * 15;
        G[12] =  SH_C0 * sh_dc[g];
        G[13] = -SH_C1 * sr[0];
        G[14] =  SH_C1 * sr[1];
        G[15] = -SH_C1 * sr[2];
        G[16] =  1.0925484305920792f  * sr[3];
        G[17] = -1.0925484305920792f  * sr[4];
        G[18] =  0.31539156525252005f * sr[5];
        G[19] = -1.0925484305920792f  * sr[6];
        G[20] =  0.5462742152960396f  * sr[7];
        G[21] = -0.5900435899266435f  * sr[8];
        G[22] =  2.890611442640554f   * sr[9];
        G[23] = -0.4570457994644658f  * sr[10];
        G[24] =  0.3731763325901154f  * sr[11];
        G[25] = -0.4570457994644658f  * sr[12];
        G[26] =  1.445305721320277f   * sr[13];
        G[27] = -0.5900435899266435f  * sr[14];
        return;
    }

    // ---- deterministic sort-scatter ----
    __shared__ int s_start[NCELL];             // counts -> exclusive starts
    __shared__ int s_pre[NCELL];               // counts in chunks < bx
    __shared__ int s_red[256];
    __shared__ unsigned short s_mycell[256];

    #pragma unroll
    for (int i = 0; i < 16; ++i) {
        s_start[tid + i * 256] = 0;
        s_pre[tid + i * 256]   = 0;
    }
    __syncthreads();

    float myx = 0.f, myy = 0.f, myz = 0.f;
    int mycell = 0;
    for (int k = 0; k < NBLK_PT; ++k) {
        int p = k * 256 + tid;
        float x = pts[3*p+0], y = pts[3*p+1], z = pts[3*p+2];
        int cell = cell_of(x, y, z);
        atomicAdd(&s_start[cell], 1);
        if (k < bx) atomicAdd(&s_pre[cell], 1);
        if (k == bx) {
            myx = x; myy = y; myz = z; mycell = cell;
            s_mycell[tid] = (unsigned short)cell;
        }
    }
    __syncthreads();

    // exclusive scan over 4096 counts (16/thread + block scan of totals)
    int base = tid * 16;
    int c[16]; int tot = 0;
    #pragma unroll
    for (int i = 0; i < 16; ++i) { c[i] = s_start[base + i]; tot += c[i]; }
    s_red[tid] = tot;
    __syncthreads();
    for (int off = 1; off < 256; off <<= 1) {
        int v = (tid >= off) ? s_red[tid - off] : 0;
        __syncthreads();
        s_red[tid] += v;
        __syncthreads();
    }
    int run = s_red[tid] - tot;
    #pragma unroll
    for (int i = 0; i < 16; ++i) { int cc = c[i]; s_start[base + i] = run; run += cc; }
    __syncthreads();

    // in-chunk stable rank among same-cell points
    int rank = 0;
    for (int t2 = 0; t2 < tid; ++t2) rank += (s_mycell[t2] == (unsigned short)mycell);

    int p_mine = bx * 256 + tid;
    int pos = s_start[mycell] + s_pre[mycell] + rank;
    spts[pos] = make_float4(myx, myy, myz, __int_as_float(p_mine));
}

// ---------------------------------------------------------------------------
// Eval body for one surviving record (R9-proven).
// ---------------------------------------------------------------------------
__device__ __forceinline__ void eval_one(
    const float* __restrict__ G, float dx, float dy, float dz, float d2,
    float& opac, float& sig)
{
    float vx = G[4]*dx + G[5]*dy + G[6]*dz;
    float vy = G[5]*dx + G[7]*dy + G[8]*dz;
    float vz = G[6]*dx + G[8]*dy + G[9]*dz;
    float maha = dx*vx + dy*vy + dz*vz;      // includes the 0.5
    float w = __expf(G[10] - maha);          // op * exp(-0.5*maha)
    opac += w;

    if (__any(w > 1e-9f)) {
        float rinv = rsqrtf(d2);
        float x = -dx * rinv, y = -dy * rinv, z = -dz * rinv;
        float xx = x*x, yy = y*y, zz = z*z;
        float xy = x*y, yz = y*z, xz = x*z;

        float res = G[12];
        res += y * G[13];
        res += z * G[14];
        res += x * G[15];
        res += xy * G[16];
        res += yz * G[17];
        res += (3.f*zz - 1.f) * G[18];
        res += xz * G[19];
        float xxmyy = xx - yy;
        res += xxmyy * G[20];
        res += y * (3.f*xx - yy) * G[21];
        res += (xy * z) * G[22];
        float f5z1 = 5.f*zz - 1.f;
        res += y * f5z1 * G[23];
        res += z * (5.f*zz - 3.f) * G[24];
        res += x * f5z1 * G[25];
        res += z * xxmyy * G[26];
        res += x * (xxmyy - 3.f*zz) * G[27];

        sig += w * fmaxf(res, 0.f);
    }
}

// ---------------------------------------------------------------------------
// N2: R9-proven main eval. Block = (256 sorted points) x (128-gaussian seg).
// AABB cull -> LDS list -> 2-way pipelined gated loop -> plain partial stores.
// ---------------------------------------------------------------------------
__global__ __launch_bounds__(BLOCK, 4) void gauss_kernel(
    const float4* __restrict__ spts, const float* __restrict__ gp,
    float2* __restrict__ part)
{
    __shared__ float s_min[4][3], s_max[4][3];
    __shared__ int s_nact;
    __shared__ int s_act[SEGSZ];

    const int tid = threadIdx.x;
    const int pb  = blockIdx.x;
    const int seg = blockIdx.y;
    float4 P = spts[pb * 256 + tid];
    const float px = P.x, py = P.y, pz = P.z;

    // block AABB
    float mnx = px, mxx = px, mny = py, mxy = py, mnz = pz, mxz = pz;
    #pragma unroll
    for (int off = 32; off >= 1; off >>= 1) {
        mnx = fminf(mnx, __shfl_xor(mnx, off));
        mxx = fmaxf(mxx, __shfl_xor(mxx, off));
        mny = fminf(mny, __shfl_xor(mny, off));
        mxy = fmaxf(mxy, __shfl_xor(mxy, off));
        mnz = fminf(mnz, __shfl_xor(mnz, off));
        mxz = fmaxf(mxz, __shfl_xor(mxz, off));
    }
    const int wave = tid >> 6;
    if ((tid & 63) == 0) {
        s_min[wave][0] = mnx; s_min[wave][1] = mny; s_min[wave][2] = mnz;
        s_max[wave][0] = mxx; s_max[wave][1] = mxy; s_max[wave][2] = mxz;
    }
    if (tid == 0) s_nact = 0;
    __syncthreads();
    const float bmnx = fminf(fminf(s_min[0][0], s_min[1][0]), fminf(s_min[2][0], s_min[3][0]));
    const float bmny = fminf(fminf(s_min[0][1], s_min[1][1]), fminf(s_min[2][1], s_min[3][1]));
    const float bmnz = fminf(fminf(s_min[0][2], s_min[1][2]), fminf(s_min[2][2], s_min[3][2]));
    const float bmxx = fmaxf(fmaxf(s_max[0][0], s_max[1][0]), fmaxf(s_max[2][0], s_max[3][0]));
    const float bmxy = fmaxf(fmaxf(s_max[0][1], s_max[1][1]), fmaxf(s_max[2][1], s_max[3][1]));
    const float bmxz = fmaxf(fmaxf(s_max[0][2], s_max[1][2]), fmaxf(s_max[2][2], s_max[3][2]));

    // conservative cull: threads 0..127 test this segment's 128 gaussians
    if (tid < SEGSZ) {
        const int gg = seg * SEGSZ + tid;
        const float* Gc = gp + (size_t)gg * GSTRIDE;
        float cx = Gc[0], cy = Gc[1], cz = Gc[2], Tg = Gc[3];
        float ddx = fmaxf(0.f, fmaxf(bmnx - cx, cx - bmxx));
        float ddy = fmaxf(0.f, fmaxf(bmny - cy, cy - bmxy));
        float ddz = fmaxf(0.f, fmaxf(bmnz - cz, cz - bmxz));
        float dd2 = ddx*ddx + ddy*ddy + ddz*ddz;
        if (dd2 <= Tg) {
            int slot = atomicAdd(&s_nact, 1);
            s_act[slot] = gg;
        }
    }
    __syncthreads();
    const int nact = s_nact;

    float opac = 0.f, sig = 0.f;
    for (int j = 0; j < nact; j += 2) {
        const bool has1 = (j + 1 < nact);
        const int g0 = __builtin_amdgcn_readfirstlane(s_act[j]);
        const int g1 = __builtin_amdgcn_readfirstlane(s_act[has1 ? j + 1 : j]);
        const float* __restrict__ A = gp + (size_t)g0 * GSTRIDE;
        const float* __restrict__ B = gp + (size_t)g1 * GSTRIDE;

        float a0 = A[0], a1 = A[1], a2 = A[2], aT = A[3];
        float b0 = B[0], b1 = B[1], b2 = B[2], bT = B[3];
        float adx = px - a0, ady = py - a1, adz = pz - a2;
        float bdx = px - b0, bdy = py - b1, bdz = pz - b2;
        float ad2 = adx*adx + ady*ady + adz*adz;
        float bd2 = bdx*bdx + bdy*bdy + bdz*bdz;

        if (!__all(ad2 > aT)) eval_one(A, adx, ady, adz, ad2, opac, sig);
        if (has1 && !__all(bd2 > bT)) eval_one(B, bdx, bdy, bdz, bd2, opac, sig);
    }

    part[((size_t)(pb * NSPLIT + seg)) * 256 + tid] = make_float2(opac, sig);
}

// ---------------------------------------------------------------------------
// N3: reduce 32 segment partials per point, write out[orig] once.
// ---------------------------------------------------------------------------
__global__ __launch_bounds__(256) void reduce_kernel(
    const float2* __restrict__ part, const float4* __restrict__ spts,
    float* __restrict__ out)
{
    const int tid = threadIdx.x, pb = blockIdx.x;
    float o = 0.f, sg = 0.f;
    #pragma unroll
    for (int s = 0; s < NSPLIT; ++s) {
        float2 v = part[((size_t)(pb * NSPLIT + s)) * 256 + tid];
        o += v.x; sg += v.y;
    }
    int orig = __float_as_int(spts[pb * 256 + tid].w);
    out[orig] = o;
    out[N_PTS + orig] = sg;
}

extern "C" void kernel_launch(void* const* d_in, const int* in_sizes, int n_in,
                              void* d_out, int out_size, void* d_ws, size_t ws_size,
                              hipStream_t stream) {
    const float* pts      = (const float*)d_in[0];
    const float* xyz      = (const float*)d_in[3];
    const float* sh_dc    = (const float*)d_in[4];
    const float* sh_rest  = (const float*)d_in[5];
    const float* scaling  = (const float*)d_in[6];
    const float* rotation = (const float*)d_in[7];
    const float* opl      = (const float*)d_in[8];

    float*  out  = (float*)d_out;
    float*  wsf  = (float*)d_ws;
    float*  gp   = wsf + WS_GP;
    float4* spts = (float4*)(wsf + WS_SPTS);
    float2* part = (float2*)(wsf + WS_PART);

    setup_kernel<<<dim3(NBLK_PT + 16), dim3(256), 0, stream>>>(
        pts, xyz, sh_dc, sh_rest, scaling, rotation, opl, gp, spts);

    dim3 grid(NBLK_PT, NSPLIT);
    gauss_kernel<<<grid, dim3(BLOCK), 0, stream>>>(spts, gp, part);
    reduce_kernel<<<dim3(NBLK_PT), dim3(256), 0, stream>>>(part, spts, out);
}

// Round 12
// 134.281 us; speedup vs baseline: 1.8565x; 1.1743x over previous
//
#include <hip/hip_runtime.h>
#include <hip/hip_bf16.h>

// ---- problem constants ----
#define N_GAUSS 4096
#define N_PTS   32768
#define BLOCK   256
#define NSPLIT  32                  // 128-gaussian segments; grid 128 x 32
#define SEGSZ   (N_GAUSS / NSPLIT)  // 128
#define NBLK_PT 128                 // 128 x 256 = 32768 points
#define GSTRIDE 28                  // floats per packed gaussian
#define NCELL   4096                // 16^3 morton cells

#define SH_C0  0.28209479177387814f
#define SH_C1  0.4886025119029199f

// Workspace layout (float index) — R9-proven footprint:
#define WS_GP     0                          // 4096*28 = 114688 floats
#define WS_GHIST  114688                     // int[4096] offsets->cursors
#define WS_CELLID 118784                     // int[32768]
#define WS_SPTS   151552                     // float4[32768]
#define WS_PART   282624                     // float2[4096*256]
// total 2,379,776 floats = 9.52 MB

__device__ __forceinline__ int cell_of(float x, float y, float z) {
    int cx = min(15, max(0, (int)((x + 3.2f) * 2.5f)));
    int cy = min(15, max(0, (int)((y + 3.2f) * 2.5f)));
    int cz = min(15, max(0, (int)((z + 3.2f) * 2.5f)));
    int ex = (cx & 1) | ((cx & 2) << 2) | ((cx & 4) << 4) | ((cx & 8) << 6);
    int ey = (cy & 1) | ((cy & 2) << 2) | ((cy & 4) << 4) | ((cy & 8) << 6);
    int ez = (cz & 1) | ((cz & 2) << 2) | ((cz & 4) << 4) | ((cz & 8) << 6);
    return ex | (ey << 1) | (ez << 2);
}

// ---------------------------------------------------------------------------
// N1 (5 blocks x 1024):
//   block 0   : bin (cell computed inline from pts, ONCE) + LDS histogram +
//               exclusive scan -> ghist offsets; also writes cellid[].
//   blocks 1-4: gaussian prep -> gp (runs on other CUs in parallel).
// Gaussian record (28 floats): [0..2] center [3] Tg cull threshold
//   [4..9] 0.5*precision [10] ln(op) [11] pad [12..27] SH pre-multiplied
// ---------------------------------------------------------------------------
__global__ __launch_bounds__(1024) void setup_kernel(
    const float* __restrict__ pts, const float* __restrict__ xyz,
    const float* __restrict__ sh_dc, const float* __restrict__ sh_rest,
    const float* __restrict__ scaling, const float* __restrict__ rotation,
    const float* __restrict__ opl, float* __restrict__ gp,
    int* __restrict__ cellid, int* __restrict__ ghist)
{
    const int t = threadIdx.x, bx = blockIdx.x;

    if (bx > 0) {
        // ---- gaussian prep: 4 blocks x 1024 = 4096 ----
        int g = (bx - 1) * 1024 + t;
        float s0 = scaling[3*g+0], s1 = scaling[3*g+1], s2 = scaling[3*g+2];
        float i0 = __expf(-2.0f * s0);
        float i1 = __expf(-2.0f * s1);
        float i2 = __expf(-2.0f * s2);
        float maxs2 = __expf(2.0f * fmaxf(s0, fmaxf(s1, s2)));

        float r = rotation[4*g+0], x = rotation[4*g+1];
        float y = rotation[4*g+2], z = rotation[4*g+3];
        float n = rsqrtf(r*r + x*x + y*y + z*z);
        r *= n; x *= n; y *= n; z *= n;
        float R00 = 1.f - 2.f*(y*y + z*z), R01 = 2.f*(x*y - r*z), R02 = 2.f*(x*z + r*y);
        float R10 = 2.f*(x*y + r*z), R11 = 1.f - 2.f*(x*x + z*z), R12 = 2.f*(y*z - r*x);
        float R20 = 2.f*(x*z - r*y), R21 = 2.f*(y*z + r*x), R22 = 1.f - 2.f*(x*x + y*y);

        float pxx = 0.5f*(R00*R00*i0 + R01*R01*i1 + R02*R02*i2);
        float pxy = 0.5f*(R00*R10*i0 + R01*R11*i1 + R02*R12*i2);
        float pxz = 0.5f*(R00*R20*i0 + R01*R21*i1 + R02*R22*i2);
        float pyy = 0.5f*(R10*R10*i0 + R11*R11*i1 + R12*R12*i2);
        float pyz = 0.5f*(R10*R20*i0 + R11*R21*i1 + R12*R22*i2);
        float pzz = 0.5f*(R20*R20*i0 + R21*R21*i1 + R22*R22*i2);

        float op   = 1.f / (1.f + __expf(-opl[g]));
        float lnop = __logf(op);
        // d2 > Tg => w < e^-16 ~ 1.1e-7; dropped total ~2e-3 << 4.1e-2 threshold
        float Tg   = 2.0f * maxs2 * (lnop + 16.0f);

        float* G = gp + (size_t)g * GSTRIDE;
        G[0] = xyz[3*g+0]; G[1] = xyz[3*g+1]; G[2] = xyz[3*g+2]; G[3] = Tg;
        G[4] = pxx; G[5] = pxy; G[6] = pxz; G[7] = pyy; G[8] = pyz; G[9] = pzz;
        G[10] = lnop; G[11] = 0.f;

        const float* sr = sh_rest + (size_t)g * 15;
        G[12] =  SH_C0 * sh_dc[g];
        G[13] = -SH_C1 * sr[0];
        G[14] =  SH_C1 * sr[1];
        G[15] = -SH_C1 * sr[2];
        G[16] =  1.0925484305920792f  * sr[3];
        G[17] = -1.0925484305920792f  * sr[4];
        G[18] =  0.31539156525252005f * sr[5];
        G[19] = -1.0925484305920792f  * sr[6];
        G[20] =  0.5462742152960396f  * sr[7];
        G[21] = -0.5900435899266435f  * sr[8];
        G[22] =  2.890611442640554f   * sr[9];
        G[23] = -0.4570457994644658f  * sr[10];
        G[24] =  0.3731763325901154f  * sr[11];
        G[25] = -0.4570457994644658f  * sr[12];
        G[26] =  1.445305721320277f   * sr[13];
        G[27] = -0.5900435899266435f  * sr[14];
        return;
    }

    // ---- block 0: bin + scan (single pass over pts, done ONCE) ----
    __shared__ int s_hist[NCELL];
    __shared__ int s_scan[1024];
    #pragma unroll
    for (int i = 0; i < 4; ++i) s_hist[t + i * 1024] = 0;
    __syncthreads();
    for (int p = t; p < N_PTS; p += 1024) {
        float x = pts[3*p+0], y = pts[3*p+1], z = pts[3*p+2];
        int cell = cell_of(x, y, z);
        cellid[p] = cell;
        atomicAdd(&s_hist[cell], 1);
    }
    __syncthreads();
    int b = t * 4;
    int c0 = s_hist[b], c1 = s_hist[b+1], c2 = s_hist[b+2], c3 = s_hist[b+3];
    int s = c0 + c1 + c2 + c3;
    s_scan[t] = s;
    __syncthreads();
    for (int off = 1; off < 1024; off <<= 1) {
        int v = (t >= off) ? s_scan[t - off] : 0;
        __syncthreads();
        s_scan[t] += v;
        __syncthreads();
    }
    int excl = s_scan[t] - s;
    ghist[b]   = excl;
    ghist[b+1] = excl + c0;
    ghist[b+2] = excl + c0 + c1;
    ghist[b+3] = excl + c0 + c1 + c2;
}

// ---------------------------------------------------------------------------
// N2: scatter points into sorted float4 (xyz + bitcast orig index).
// ghist doubles as the cursor array (R9-proven).
// ---------------------------------------------------------------------------
__global__ __launch_bounds__(256) void scatter_kernel(
    const float* __restrict__ pts, const int* __restrict__ cellid,
    int* __restrict__ ghist, float4* __restrict__ spts)
{
    int p = blockIdx.x * 256 + threadIdx.x;
    float x = pts[3*p+0], y = pts[3*p+1], z = pts[3*p+2];
    int pos = atomicAdd(&ghist[cellid[p]], 1);
    spts[pos] = make_float4(x, y, z, __int_as_float(p));
}

// ---------------------------------------------------------------------------
// Eval body for one surviving record (R9-proven).
// ---------------------------------------------------------------------------
__device__ __forceinline__ void eval_one(
    const float* __restrict__ G, float dx, float dy, float dz, float d2,
    float& opac, float& sig)
{
    float vx = G[4]*dx + G[5]*dy + G[6]*dz;
    float vy = G[5]*dx + G[7]*dy + G[8]*dz;
    float vz = G[6]*dx + G[8]*dy + G[9]*dz;
    float maha = dx*vx + dy*vy + dz*vz;      // includes the 0.5
    float w = __expf(G[10] - maha);          // op * exp(-0.5*maha)
    opac += w;

    if (__any(w > 1e-9f)) {
        float rinv = rsqrtf(d2);
        float x = -dx * rinv, y = -dy * rinv, z = -dz * rinv;
        float xx = x*x, yy = y*y, zz = z*z;
        float xy = x*y, yz = y*z, xz = x*z;

        float res = G[12];
        res += y * G[13];
        res += z * G[14];
        res += x * G[15];
        res += xy * G[16];
        res += yz * G[17];
        res += (3.f*zz - 1.f) * G[18];
        res += xz * G[19];
        float xxmyy = xx - yy;
        res += xxmyy * G[20];
        res += y * (3.f*xx - yy) * G[21];
        res += (xy * z) * G[22];
        float f5z1 = 5.f*zz - 1.f;
        res += y * f5z1 * G[23];
        res += z * (5.f*zz - 3.f) * G[24];
        res += x * f5z1 * G[25];
        res += z * xxmyy * G[26];
        res += x * (xxmyy - 3.f*zz) * G[27];

        sig += w * fmaxf(res, 0.f);
    }
}

// ---------------------------------------------------------------------------
// N3: R9-proven main eval. Block = (256 sorted points) x (128-gaussian seg).
// AABB cull -> LDS list -> 2-way pipelined gated loop -> plain partial stores.
// ---------------------------------------------------------------------------
__global__ __launch_bounds__(BLOCK, 4) void gauss_kernel(
    const float4* __restrict__ spts, const float* __restrict__ gp,
    float2* __restrict__ part)
{
    __shared__ float s_min[4][3], s_max[4][3];
    __shared__ int s_nact;
    __shared__ int s_act[SEGSZ];

    const int tid = threadIdx.x;
    const int pb  = blockIdx.x;
    const int seg = blockIdx.y;
    float4 P = spts[pb * 256 + tid];
    const float px = P.x, py = P.y, pz = P.z;

    // block AABB
    float mnx = px, mxx = px, mny = py, mxy = py, mnz = pz, mxz = pz;
    #pragma unroll
    for (int off = 32; off >= 1; off >>= 1) {
        mnx = fminf(mnx, __shfl_xor(mnx, off));
        mxx = fmaxf(mxx, __shfl_xor(mxx, off));
        mny = fminf(mny, __shfl_xor(mny, off));
        mxy = fmaxf(mxy, __shfl_xor(mxy, off));
        mnz = fminf(mnz, __shfl_xor(mnz, off));
        mxz = fmaxf(mxz, __shfl_xor(mxz, off));
    }
    const int wave = tid >> 6;
    if ((tid & 63) == 0) {
        s_min[wave][0] = mnx; s_min[wave][1] = mny; s_min[wave][2] = mnz;
        s_max[wave][0] = mxx; s_max[wave][1] = mxy; s_max[wave][2] = mxz;
    }
    if (tid == 0) s_nact = 0;
    __syncthreads();
    const float bmnx = fminf(fminf(s_min[0][0], s_min[1][0]), fminf(s_min[2][0], s_min[3][0]));
    const float bmny = fminf(fminf(s_min[0][1], s_min[1][1]), fminf(s_min[2][1], s_min[3][1]));
    const float bmnz = fminf(fminf(s_min[0][2], s_min[1][2]), fminf(s_min[2][2], s_min[3][2]));
    const float bmxx = fmaxf(fmaxf(s_max[0][0], s_max[1][0]), fmaxf(s_max[2][0], s_max[3][0]));
    const float bmxy = fmaxf(fmaxf(s_max[0][1], s_max[1][1]), fmaxf(s_max[2][1], s_max[3][1]));
    const float bmxz = fmaxf(fmaxf(s_max[0][2], s_max[1][2]), fmaxf(s_max[2][2], s_max[3][2]));

    // conservative cull: threads 0..127 test this segment's 128 gaussians
    if (tid < SEGSZ) {
        const int gg = seg * SEGSZ + tid;
        const float* Gc = gp + (size_t)gg * GSTRIDE;
        float cx = Gc[0], cy = Gc[1], cz = Gc[2], Tg = Gc[3];
        float ddx = fmaxf(0.f, fmaxf(bmnx - cx, cx - bmxx));
        float ddy = fmaxf(0.f, fmaxf(bmny - cy, cy - bmxy));
        float ddz = fmaxf(0.f, fmaxf(bmnz - cz, cz - bmxz));
        float dd2 = ddx*ddx + ddy*ddy + ddz*ddz;
        if (dd2 <= Tg) {
            int slot = atomicAdd(&s_nact, 1);
            s_act[slot] = gg;
        }
    }
    __syncthreads();
    const int nact = s_nact;

    float opac = 0.f, sig = 0.f;
    for (int j = 0; j < nact; j += 2) {
        const bool has1 = (j + 1 < nact);
        const int g0 = __builtin_amdgcn_readfirstlane(s_act[j]);
        const int g1 = __builtin_amdgcn_readfirstlane(s_act[has1 ? j + 1 : j]);
        const float* __restrict__ A = gp + (size_t)g0 * GSTRIDE;
        const float* __restrict__ B = gp + (size_t)g1 * GSTRIDE;

        float a0 = A[0], a1 = A[1], a2 = A[2], aT = A[3];
        float b0 = B[0], b1 = B[1], b2 = B[2], bT = B[3];
        float adx = px - a0, ady = py - a1, adz = pz - a2;
        float bdx = px - b0, bdy = py - b1, bdz = pz - b2;
        float ad2 = adx*adx + ady*ady + adz*adz;
        float bd2 = bdx*bdx + bdy*bdy + bdz*bdz;

        if (!__all(ad2 > aT)) eval_one(A, adx, ady, adz, ad2, opac, sig);
        if (has1 && !__all(bd2 > bT)) eval_one(B, bdx, bdy, bdz, bd2, opac, sig);
    }

    part[((size_t)(pb * NSPLIT + seg)) * 256 + tid] = make_float2(opac, sig);
}

// ---------------------------------------------------------------------------
// N4: reduce 32 segment partials per point, write out[orig] once.
// ---------------------------------------------------------------------------
__global__ __launch_bounds__(256) void reduce_kernel(
    const float2* __restrict__ part, const float4* __restrict__ spts,
    float* __restrict__ out)
{
    const int tid = threadIdx.x, pb = blockIdx.x;
    float o = 0.f, sg = 0.f;
    #pragma unroll
    for (int s = 0; s < NSPLIT; ++s) {
        float2 v = part[((size_t)(pb * NSPLIT + s)) * 256 + tid];
        o += v.x; sg += v.y;
    }
    int orig = __float_as_int(spts[pb * 256 + tid].w);
    out[orig] = o;
    out[N_PTS + orig] = sg;
}

extern "C" void kernel_launch(void* const* d_in, const int* in_sizes, int n_in,
                              void* d_out, int out_size, void* d_ws, size_t ws_size,
                              hipStream_t stream) {
    const float* pts      = (const float*)d_in[0];
    const float* xyz      = (const float*)d_in[3];
    const float* sh_dc    = (const float*)d_in[4];
    const float* sh_rest  = (const float*)d_in[5];
    const float* scaling  = (const float*)d_in[6];
    const float* rotation = (const float*)d_in[7];
    const float* opl      = (const float*)d_in[8];

    float*  out    = (float*)d_out;
    float*  wsf    = (float*)d_ws;
    float*  gp     = wsf + WS_GP;
    int*    ghist  = (int*)(wsf + WS_GHIST);
    int*    cellid = (int*)(wsf + WS_CELLID);
    float4* spts   = (float4*)(wsf + WS_SPTS);
    float2* part   = (float2*)(wsf + WS_PART);

    setup_kernel<<<dim3(5), dim3(1024), 0, stream>>>(
        pts, xyz, sh_dc, sh_rest, scaling, rotation, opl, gp, cellid, ghist);
    scatter_kernel<<<dim3(NBLK_PT), dim3(256), 0, stream>>>(pts, cellid, ghist, spts);

    dim3 grid(NBLK_PT, NSPLIT);
    gauss_kernel<<<grid, dim3(BLOCK), 0, stream>>>(spts, gp, part);
    reduce_kernel<<<dim3(NBLK_PT), dim3(256), 0, stream>>>(part, spts, out);
}

// Round 13
// 128.604 us; speedup vs baseline: 1.9385x; 1.0441x over previous
//
#include <hip/hip_runtime.h>
#include <hip/hip_bf16.h>

// ---- problem constants ----
#define N_GAUSS 4096
#define N_PTS   32768
#define BLOCK   256
#define NSPLIT  64                  // 64-gaussian segments; grid 128 x 64
#define SEGSZ   (N_GAUSS / NSPLIT)  // 64
#define NBLK_PT 128                 // 128 x 256 = 32768 points
#define GSTRIDE 28                  // floats per packed gaussian
#define NCELL   4096                // 16^3 morton cells

#define SH_C0  0.28209479177387814f
#define SH_C1  0.4886025119029199f

// Workspace layout (float index):
#define WS_GP     0                          // 4096*28 = 114688 floats
#define WS_GHIST  114688                     // int[4096] offsets->cursors
#define WS_CELLID 118784                     // int[32768]
#define WS_SPTS   151552                     // float4[32768] = 131072 floats
#define WS_ACC    282624                     // float[2*32768] sorted-index accumulators
// total 348,160 floats = 1.39 MB

__device__ __forceinline__ int cell_of(float x, float y, float z) {
    int cx = min(15, max(0, (int)((x + 3.2f) * 2.5f)));
    int cy = min(15, max(0, (int)((y + 3.2f) * 2.5f)));
    int cz = min(15, max(0, (int)((z + 3.2f) * 2.5f)));
    int ex = (cx & 1) | ((cx & 2) << 2) | ((cx & 4) << 4) | ((cx & 8) << 6);
    int ey = (cy & 1) | ((cy & 2) << 2) | ((cy & 4) << 4) | ((cy & 8) << 6);
    int ez = (cz & 1) | ((cz & 2) << 2) | ((cz & 4) << 4) | ((cz & 8) << 6);
    return ex | (ey << 1) | (ez << 2);
}

// ---------------------------------------------------------------------------
// N1 (7 blocks x 1024):
//   block 0   : bin (cell inline from pts) + LDS histogram + exclusive scan
//               -> ghist offsets; writes cellid[].
//   blocks 1-4: gaussian prep -> gp.
//   blocks 5-6: zero acc (2 x 1024 x 8 float4 = 65536 floats).
// ---------------------------------------------------------------------------
__global__ __launch_bounds__(1024) void setup_kernel(
    const float* __restrict__ pts, const float* __restrict__ xyz,
    const float* __restrict__ sh_dc, const float* __restrict__ sh_rest,
    const float* __restrict__ scaling, const float* __restrict__ rotation,
    const float* __restrict__ opl, float* __restrict__ gp,
    int* __restrict__ cellid, int* __restrict__ ghist, float* __restrict__ acc)
{
    const int t = threadIdx.x, bx = blockIdx.x;

    if (bx >= 5) {
        // ---- zero acc ----
        float4* a4 = (float4*)acc;
        int base = (bx - 5) * 1024 * 8 + t;
        #pragma unroll
        for (int i = 0; i < 8; ++i) a4[base + i * 1024] = make_float4(0.f, 0.f, 0.f, 0.f);
        return;
    }
    if (bx > 0) {
        // ---- gaussian prep: 4 blocks x 1024 = 4096 ----
        int g = (bx - 1) * 1024 + t;
        float s0 = scaling[3*g+0], s1 = scaling[3*g+1], s2 = scaling[3*g+2];
        float i0 = __expf(-2.0f * s0);
        float i1 = __expf(-2.0f * s1);
        float i2 = __expf(-2.0f * s2);
        float maxs2 = __expf(2.0f * fmaxf(s0, fmaxf(s1, s2)));

        float r = rotation[4*g+0], x = rotation[4*g+1];
        float y = rotation[4*g+2], z = rotation[4*g+3];
        float n = rsqrtf(r*r + x*x + y*y + z*z);
        r *= n; x *= n; y *= n; z *= n;
        float R00 = 1.f - 2.f*(y*y + z*z), R01 = 2.f*(x*y - r*z), R02 = 2.f*(x*z + r*y);
        float R10 = 2.f*(x*y + r*z), R11 = 1.f - 2.f*(x*x + z*z), R12 = 2.f*(y*z - r*x);
        float R20 = 2.f*(x*z - r*y), R21 = 2.f*(y*z + r*x), R22 = 1.f - 2.f*(x*x + y*y);

        float pxx = 0.5f*(R00*R00*i0 + R01*R01*i1 + R02*R02*i2);
        float pxy = 0.5f*(R00*R10*i0 + R01*R11*i1 + R02*R12*i2);
        float pxz = 0.5f*(R00*R20*i0 + R01*R21*i1 + R02*R22*i2);
        float pyy = 0.5f*(R10*R10*i0 + R11*R11*i1 + R12*R12*i2);
        float pyz = 0.5f*(R10*R20*i0 + R11*R21*i1 + R12*R22*i2);
        float pzz = 0.5f*(R20*R20*i0 + R21*R21*i1 + R22*R22*i2);

        float op   = 1.f / (1.f + __expf(-opl[g]));
        float lnop = __logf(op);
        // d2 > Tg => w < e^-16 ~ 1.1e-7; dropped total ~2e-3 << 4.1e-2 threshold
        float Tg   = 2.0f * maxs2 * (lnop + 16.0f);

        float* G = gp + (size_t)g * GSTRIDE;
        G[0] = xyz[3*g+0]; G[1] = xyz[3*g+1]; G[2] = xyz[3*g+2]; G[3] = Tg;
        G[4] = pxx; G[5] = pxy; G[6] = pxz; G[7] = pyy; G[8] = pyz; G[9] = pzz;
        G[10] = lnop; G[11] = 0.f;

        const float* sr = sh_rest + (size_t)g * 15;
        G[12] =  SH_C0 * sh_dc[g];
        G[13] = -SH_C1 * sr[0];
        G[14] =  SH_C1 * sr[1];
        G[15] = -SH_C1 * sr[2];
        G[16] =  1.0925484305920792f  * sr[3];
        G[17] = -1.0925484305920792f  * sr[4];
        G[18] =  0.31539156525252005f * sr[5];
        G[19] = -1.0925484305920792f  * sr[6];
        G[20] =  0.5462742152960396f  * sr[7];
        G[21] = -0.5900435899266435f  * sr[8];
        G[22] =  2.890611442640554f   * sr[9];
        G[23] = -0.4570457994644658f  * sr[10];
        G[24] =  0.3731763325901154f  * sr[11];
        G[25] = -0.4570457994644658f  * sr[12];
        G[26] =  1.445305721320277f   * sr[13];
        G[27] = -0.5900435899266435f  * sr[14];
        return;
    }

    // ---- block 0: bin + scan ----
    __shared__ int s_hist[NCELL];
    __shared__ int s_scan[1024];
    #pragma unroll
    for (int i = 0; i < 4; ++i) s_hist[t + i * 1024] = 0;
    __syncthreads();
    for (int p = t; p < N_PTS; p += 1024) {
        float x = pts[3*p+0], y = pts[3*p+1], z = pts[3*p+2];
        int cell = cell_of(x, y, z);
        cellid[p] = cell;
        atomicAdd(&s_hist[cell], 1);
    }
    __syncthreads();
    int b = t * 4;
    int c0 = s_hist[b], c1 = s_hist[b+1], c2 = s_hist[b+2], c3 = s_hist[b+3];
    int s = c0 + c1 + c2 + c3;
    s_scan[t] = s;
    __syncthreads();
    for (int off = 1; off < 1024; off <<= 1) {
        int v = (t >= off) ? s_scan[t - off] : 0;
        __syncthreads();
        s_scan[t] += v;
        __syncthreads();
    }
    int excl = s_scan[t] - s;
    ghist[b]   = excl;
    ghist[b+1] = excl + c0;
    ghist[b+2] = excl + c0 + c1;
    ghist[b+3] = excl + c0 + c1 + c2;
}

// ---------------------------------------------------------------------------
// N2: scatter points into sorted float4 (xyz + bitcast orig index).
// ---------------------------------------------------------------------------
__global__ __launch_bounds__(256) void scatter_kernel(
    const float* __restrict__ pts, const int* __restrict__ cellid,
    int* __restrict__ ghist, float4* __restrict__ spts)
{
    int p = blockIdx.x * 256 + threadIdx.x;
    float x = pts[3*p+0], y = pts[3*p+1], z = pts[3*p+2];
    int pos = atomicAdd(&ghist[cellid[p]], 1);
    spts[pos] = make_float4(x, y, z, __int_as_float(p));
}

// ---------------------------------------------------------------------------
// Eval body for one surviving record (R9-proven).
// ---------------------------------------------------------------------------
__device__ __forceinline__ void eval_one(
    const float* __restrict__ G, float dx, float dy, float dz, float d2,
    float& opac, float& sig)
{
    float vx = G[4]*dx + G[5]*dy + G[6]*dz;
    float vy = G[5]*dx + G[7]*dy + G[8]*dz;
    float vz = G[6]*dx + G[8]*dy + G[9]*dz;
    float maha = dx*vx + dy*vy + dz*vz;      // includes the 0.5
    float w = __expf(G[10] - maha);          // op * exp(-0.5*maha)
    opac += w;

    if (__any(w > 1e-9f)) {
        float rinv = rsqrtf(d2);
        float x = -dx * rinv, y = -dy * rinv, z = -dz * rinv;
        float xx = x*x, yy = y*y, zz = z*z;
        float xy = x*y, yz = y*z, xz = x*z;

        float res = G[12];
        res += y * G[13];
        res += z * G[14];
        res += x * G[15];
        res += xy * G[16];
        res += yz * G[17];
        res += (3.f*zz - 1.f) * G[18];
        res += xz * G[19];
        float xxmyy = xx - yy;
        res += xxmyy * G[20];
        res += y * (3.f*xx - yy) * G[21];
        res += (xy * z) * G[22];
        float f5z1 = 5.f*zz - 1.f;
        res += y * f5z1 * G[23];
        res += z * (5.f*zz - 3.f) * G[24];
        res += x * f5z1 * G[25];
        res += z * xxmyy * G[26];
        res += x * (xxmyy - 3.f*zz) * G[27];

        sig += w * fmaxf(res, 0.f);
    }
}

// ---------------------------------------------------------------------------
// N3: main eval. Block = (256 sorted points) x (64-gaussian segment).
// AABB cull -> LDS list -> 2-way pipelined gated loop -> COALESCED atomic
// accumulation into sorted-index acc (64 consecutive floats per wave).
// ---------------------------------------------------------------------------
__global__ __launch_bounds__(BLOCK, 4) void gauss_kernel(
    const float4* __restrict__ spts, const float* __restrict__ gp,
    float* __restrict__ acc)
{
    __shared__ float s_min[4][3], s_max[4][3];
    __shared__ int s_nact;
    __shared__ int s_act[SEGSZ];

    const int tid = threadIdx.x;
    const int pb  = blockIdx.x;
    const int seg = blockIdx.y;
    float4 P = spts[pb * 256 + tid];
    const float px = P.x, py = P.y, pz = P.z;

    // block AABB
    float mnx = px, mxx = px, mny = py, mxy = py, mnz = pz, mxz = pz;
    #pragma unroll
    for (int off = 32; off >= 1; off >>= 1) {
        mnx = fminf(mnx, __shfl_xor(mnx, off));
        mxx = fmaxf(mxx, __shfl_xor(mxx, off));
        mny = fminf(mny, __shfl_xor(mny, off));
        mxy = fmaxf(mxy, __shfl_xor(mxy, off));
        mnz = fminf(mnz, __shfl_xor(mnz, off));
        mxz = fmaxf(mxz, __shfl_xor(mxz, off));
    }
    const int wave = tid >> 6;
    if ((tid & 63) == 0) {
        s_min[wave][0] = mnx; s_min[wave][1] = mny; s_min[wave][2] = mnz;
        s_max[wave][0] = mxx; s_max[wave][1] = mxy; s_max[wave][2] = mxz;
    }
    if (tid == 0) s_nact = 0;
    __syncthreads();
    const float bmnx = fminf(fminf(s_min[0][0], s_min[1][0]), fminf(s_min[2][0], s_min[3][0]));
    const float bmny = fminf(fminf(s_min[0][1], s_min[1][1]), fminf(s_min[2][1], s_min[3][1]));
    const float bmnz = fminf(fminf(s_min[0][2], s_min[1][2]), fminf(s_min[2][2], s_min[3][2]));
    const float bmxx = fmaxf(fmaxf(s_max[0][0], s_max[1][0]), fmaxf(s_max[2][0], s_max[3][0]));
    const float bmxy = fmaxf(fmaxf(s_max[0][1], s_max[1][1]), fmaxf(s_max[2][1], s_max[3][1]));
    const float bmxz = fmaxf(fmaxf(s_max[0][2], s_max[1][2]), fmaxf(s_max[2][2], s_max[3][2]));

    // conservative cull: threads 0..63 test this segment's 64 gaussians
    if (tid < SEGSZ) {
        const int gg = seg * SEGSZ + tid;
        const float* Gc = gp + (size_t)gg * GSTRIDE;
        float cx = Gc[0], cy = Gc[1], cz = Gc[2], Tg = Gc[3];
        float ddx = fmaxf(0.f, fmaxf(bmnx - cx, cx - bmxx));
        float ddy = fmaxf(0.f, fmaxf(bmny - cy, cy - bmxy));
        float ddz = fmaxf(0.f, fmaxf(bmnz - cz, cz - bmxz));
        float dd2 = ddx*ddx + ddy*ddy + ddz*ddz;
        if (dd2 <= Tg) {
            int slot = atomicAdd(&s_nact, 1);
            s_act[slot] = gg;
        }
    }
    __syncthreads();
    const int nact = s_nact;
    if (nact == 0) return;

    float opac = 0.f, sig = 0.f;
    for (int j = 0; j < nact; j += 2) {
        const bool has1 = (j + 1 < nact);
        const int g0 = __builtin_amdgcn_readfirstlane(s_act[j]);
        const int g1 = __builtin_amdgcn_readfirstlane(s_act[has1 ? j + 1 : j]);
        const float* __restrict__ A = gp + (size_t)g0 * GSTRIDE;
        const float* __restrict__ B = gp + (size_t)g1 * GSTRIDE;

        float a0 = A[0], a1 = A[1], a2 = A[2], aT = A[3];
        float b0 = B[0], b1 = B[1], b2 = B[2], bT = B[3];
        float adx = px - a0, ady = py - a1, adz = pz - a2;
        float bdx = px - b0, bdy = py - b1, bdz = pz - b2;
        float ad2 = adx*adx + ady*ady + adz*adz;
        float bd2 = bdx*bdx + bdy*bdy + bdz*bdz;

        if (!__all(ad2 > aT)) eval_one(A, adx, ady, adz, ad2, opac, sig);
        if (has1 && !__all(bd2 > bT)) eval_one(B, bdx, bdy, bdz, bd2, opac, sig);
    }

    // coalesced atomics: wave hits 64 consecutive floats (4 cache lines)
    const int pos = pb * 256 + tid;
    atomicAdd(&acc[pos], opac);
    atomicAdd(&acc[N_PTS + pos], sig);
}

// ---------------------------------------------------------------------------
// N4: permute acc (sorted index) -> out (original index), plain stores.
// ---------------------------------------------------------------------------
__global__ __launch_bounds__(256) void permute_kernel(
    const float* __restrict__ acc, const float4* __restrict__ spts,
    float* __restrict__ out)
{
    int p = blockIdx.x * 256 + threadIdx.x;
    int orig = __float_as_int(spts[p].w);
    out[orig] = acc[p];
    out[N_PTS + orig] = acc[N_PTS + p];
}

extern "C" void kernel_launch(void* const* d_in, const int* in_sizes, int n_in,
                              void* d_out, int out_size, void* d_ws, size_t ws_size,
                              hipStream_t stream) {
    const float* pts      = (const float*)d_in[0];
    const float* xyz      = (const float*)d_in[3];
    const float* sh_dc    = (const float*)d_in[4];
    const float* sh_rest  = (const float*)d_in[5];
    const float* scaling  = (const float*)d_in[6];
    const float* rotation = (const float*)d_in[7];
    const float* opl      = (const float*)d_in[8];

    float*  out    = (float*)d_out;
    float*  wsf    = (float*)d_ws;
    float*  gp     = wsf + WS_GP;
    int*    ghist  = (int*)(wsf + WS_GHIST);
    int*    cellid = (int*)(wsf + WS_CELLID);
    float4* spts   = (float4*)(wsf + WS_SPTS);
    float*  acc    = wsf + WS_ACC;

    setup_kernel<<<dim3(7), dim3(1024), 0, stream>>>(
        pts, xyz, sh_dc, sh_rest, scaling, rotation, opl, gp, cellid, ghist, acc);
    scatter_kernel<<<dim3(NBLK_PT), dim3(256), 0, stream>>>(pts, cellid, ghist, spts);

    dim3 grid(NBLK_PT, NSPLIT);
    gauss_kernel<<<grid, dim3(BLOCK), 0, stream>>>(spts, gp, acc);
    permute_kernel<<<dim3(NBLK_PT), dim3(256), 0, stream>>>(acc, spts, out);
}